// Round 1
// baseline (5355.426 us; speedup 1.0000x reference)
//
#include <hip/hip_runtime.h>

// LSTM_61203283968689 — fused 3-layer LSTM, f16-dot2, persistent per-block scan.
// B=1024, T=512, IN=22, H=64. 256 blocks x 512 threads; 4 samples/block.
// Thread = (j in [0,64), s in [0,4), half in {0,1}); half0 -> gate rows {j, j+64} (i,f),
// half1 -> rows {j+128, j+192} (g,o). Partner exchange via shfl_xor(1) (same wave).
// Weights: L0 in registers (86 f16-pairs/thread), L1/L2 in LDS f16 (row stride 66 dwords
// -> bank-stride 2, conflict-free; 4 samples broadcast the same weight dwords).
// h ping-pong in LDS (f16), c fp32 in registers. 3 barriers/step.

#define BSZ 1024
#define TT 512
#define IN_DIM 22
#define HDIM 64
#define NG 256
#define GS 4
#define NTH 512

typedef _Float16 h16;
typedef __attribute__((ext_vector_type(2))) _Float16 h16x2;

#if __has_builtin(__builtin_amdgcn_fdot2)
__device__ __forceinline__ float fdot2f(h16x2 a, h16x2 b, float c) {
    return __builtin_amdgcn_fdot2(a, b, c, false);
}
#else
__device__ __forceinline__ float fdot2f(h16x2 a, h16x2 b, float c) {
    return c + (float)a[0] * (float)b[0] + (float)a[1] * (float)b[1];
}
#endif

__device__ __forceinline__ float sigf(float z)   { return 1.f / (1.f + __expf(-z)); }
__device__ __forceinline__ float tanhf_(float z) { return 1.f - 2.f / (1.f + __expf(2.f * z)); }

__global__ __launch_bounds__(NTH, 2) void lstm_fused(
    const float* __restrict__ x,
    const float* __restrict__ wih0, const float* __restrict__ whh0,
    const float* __restrict__ bih0, const float* __restrict__ bhh0,
    const float* __restrict__ wih1, const float* __restrict__ whh1,
    const float* __restrict__ bih1, const float* __restrict__ bhh1,
    const float* __restrict__ wih2, const float* __restrict__ whh2,
    const float* __restrict__ bih2, const float* __restrict__ bhh2,
    const float* __restrict__ wfc, const float* __restrict__ bfc,
    float* __restrict__ out)
{
    const int tid  = threadIdx.x;
    const int half = tid & 1;
    const int s    = (tid >> 1) & 3;
    const int j    = tid >> 3;
    const int b4   = blockIdx.x * GS;

    // LDS: 2*67584 + 3328 + 384 + 1088 = 139,968 B (< 160 KiB)
    __shared__ h16x2 WL1[NG * 66];
    __shared__ h16x2 WL2[NG * 66];
    __shared__ h16x2 HA[2][GS][104];   // per sample: h0[0..31], h1[32..63], h2[64..95], pad
    __shared__ h16x2 XA[GS][12];       // x_t, 11 pair-dwords used
    __shared__ float HF[GS][68];       // final h2 in fp32 for FC

    const int r0 = j + 64 * (half * 2 + 0);
    const int r1 = j + 64 * (half * 2 + 1);

    // ---- stage L1/L2 weights into LDS as f16 pairs (row = [w_ih row | w_hh row]) ----
    for (int idx = tid; idx < NG * 64; idx += NTH) {
        const int r = idx >> 6, kk = idx & 63;
        float a, b;
        h16x2 p;
        if (kk < 32) { a = wih1[r * 64 + 2 * kk];        b = wih1[r * 64 + 2 * kk + 1]; }
        else         { a = whh1[r * 64 + 2 * (kk - 32)]; b = whh1[r * 64 + 2 * (kk - 32) + 1]; }
        p[0] = (h16)a; p[1] = (h16)b;
        WL1[r * 66 + kk] = p;
        if (kk < 32) { a = wih2[r * 64 + 2 * kk];        b = wih2[r * 64 + 2 * kk + 1]; }
        else         { a = whh2[r * 64 + 2 * (kk - 32)]; b = whh2[r * 64 + 2 * (kk - 32) + 1]; }
        p[0] = (h16)a; p[1] = (h16)b;
        WL2[r * 66 + kk] = p;
    }

    // ---- L0 weights into registers: [x(22) | h0(64)] -> 43 pair-dwords per row ----
    h16x2 w0[2][43];
    #pragma unroll
    for (int mi = 0; mi < 2; ++mi) {
        const int r = j + 64 * (half * 2 + mi);
        #pragma unroll
        for (int kk = 0; kk < 11; ++kk) {
            h16x2 p;
            p[0] = (h16)wih0[r * IN_DIM + 2 * kk];
            p[1] = (h16)wih0[r * IN_DIM + 2 * kk + 1];
            w0[mi][kk] = p;
        }
        #pragma unroll
        for (int kk = 0; kk < 32; ++kk) {
            h16x2 p;
            p[0] = (h16)whh0[r * 64 + 2 * kk];
            p[1] = (h16)whh0[r * 64 + 2 * kk + 1];
            w0[mi][11 + kk] = p;
        }
    }

    // biases (b_ih + b_hh folded)
    float bs0[2], bs1[2], bs2[2];
    bs0[0] = bih0[r0] + bhh0[r0]; bs0[1] = bih0[r1] + bhh0[r1];
    bs1[0] = bih1[r0] + bhh1[r0]; bs1[1] = bih1[r1] + bhh1[r1];
    bs2[0] = bih2[r0] + bhh2[r0]; bs2[1] = bih2[r1] + bhh2[r1];

    // zero h ping-pong
    {
        h16x2 z; z[0] = (h16)0.f; z[1] = (h16)0.f;
        h16x2* hp = &HA[0][0][0];
        for (int idx = tid; idx < 2 * GS * 104; idx += NTH) hp[idx] = z;
    }
    // stage x_0
    if (tid < GS * IN_DIM) {
        const int ss = tid / IN_DIM, ii = tid % IN_DIM;
        ((h16*)&XA[ss][0])[ii] = (h16)x[(size_t)(b4 + ss) * (IN_DIM * TT) + ii * TT + 0];
    }
    float c0 = 0.f, c1 = 0.f, c2 = 0.f;
    float h2last = 0.f;
    __syncthreads();

    const h16x2* w1p0 = &WL1[r0 * 66];
    const h16x2* w1p1 = &WL1[r1 * 66];
    const h16x2* w2p0 = &WL2[r0 * 66];
    const h16x2* w2p1 = &WL2[r1 * 66];

    #pragma unroll 1
    for (int t = 0; t < TT; ++t) {
        const int op = t & 1, np = op ^ 1;
        const h16x2* hold  = &HA[op][s][0];
        const h16x2* hnew  = &HA[np][s][0];
        h16*         hnewh = (h16*)&HA[np][s][0];

        // ================= Layer 0 : gates = W0 * [x_t ; h0_old] =================
        {
            float a0 = bs0[0], a1 = bs0[1], b0 = 0.f, b1 = 0.f;
            #pragma unroll
            for (int kk = 0; kk < 10; kk += 2) {
                h16x2 v  = XA[s][kk];
                h16x2 v2 = XA[s][kk + 1];
                a0 = fdot2f(w0[0][kk],     v,  a0);  a1 = fdot2f(w0[1][kk],     v,  a1);
                b0 = fdot2f(w0[0][kk + 1], v2, b0);  b1 = fdot2f(w0[1][kk + 1], v2, b1);
            }
            { h16x2 v = XA[s][10];
              a0 = fdot2f(w0[0][10], v, a0);  a1 = fdot2f(w0[1][10], v, a1); }
            #pragma unroll
            for (int kk = 0; kk < 32; kk += 2) {
                h16x2 v  = hold[kk];
                h16x2 v2 = hold[kk + 1];
                a0 = fdot2f(w0[0][11 + kk],     v,  a0);  a1 = fdot2f(w0[1][11 + kk],     v,  a1);
                b0 = fdot2f(w0[0][11 + kk + 1], v2, b0);  b1 = fdot2f(w0[1][11 + kk + 1], v2, b1);
            }
            a0 += b0; a1 += b1;
            const float pa0 = __shfl_xor(a0, 1);
            const float pa1 = __shfl_xor(a1, 1);
            if (half == 0) {
                const float ig = sigf(a0), fg = sigf(a1), gg = tanhf_(pa0), og = sigf(pa1);
                c0 = fg * c0 + ig * gg;
                hnewh[0 + j] = (h16)(og * tanhf_(c0));
            }
        }
        __syncthreads();

        // ============ Layer 1 : gates = W1 * [h0_new ; h1_old] ============
        {
            float a0 = bs1[0], a1 = bs1[1], b0 = 0.f, b1 = 0.f;
            #pragma unroll
            for (int kk = 0; kk < 32; kk += 2) {
                h16x2 v  = hnew[kk];
                h16x2 v2 = hnew[kk + 1];
                a0 = fdot2f(w1p0[kk],     v,  a0);  a1 = fdot2f(w1p1[kk],     v,  a1);
                b0 = fdot2f(w1p0[kk + 1], v2, b0);  b1 = fdot2f(w1p1[kk + 1], v2, b1);
            }
            #pragma unroll
            for (int kk = 0; kk < 32; kk += 2) {
                h16x2 v  = hold[32 + kk];
                h16x2 v2 = hold[32 + kk + 1];
                a0 = fdot2f(w1p0[32 + kk],     v,  a0);  a1 = fdot2f(w1p1[32 + kk],     v,  a1);
                b0 = fdot2f(w1p0[32 + kk + 1], v2, b0);  b1 = fdot2f(w1p1[32 + kk + 1], v2, b1);
            }
            a0 += b0; a1 += b1;
            const float pa0 = __shfl_xor(a0, 1);
            const float pa1 = __shfl_xor(a1, 1);
            if (half == 0) {
                const float ig = sigf(a0), fg = sigf(a1), gg = tanhf_(pa0), og = sigf(pa1);
                c1 = fg * c1 + ig * gg;
                hnewh[64 + j] = (h16)(og * tanhf_(c1));
            }
        }
        __syncthreads();

        // ============ Layer 2 : gates = W2 * [h1_new ; h2_old] ============
        {
            float a0 = bs2[0], a1 = bs2[1], b0 = 0.f, b1 = 0.f;
            #pragma unroll
            for (int kk = 0; kk < 32; kk += 2) {
                h16x2 v  = hnew[32 + kk];
                h16x2 v2 = hnew[32 + kk + 1];
                a0 = fdot2f(w2p0[kk],     v,  a0);  a1 = fdot2f(w2p1[kk],     v,  a1);
                b0 = fdot2f(w2p0[kk + 1], v2, b0);  b1 = fdot2f(w2p1[kk + 1], v2, b1);
            }
            #pragma unroll
            for (int kk = 0; kk < 32; kk += 2) {
                h16x2 v  = hold[64 + kk];
                h16x2 v2 = hold[64 + kk + 1];
                a0 = fdot2f(w2p0[32 + kk],     v,  a0);  a1 = fdot2f(w2p1[32 + kk],     v,  a1);
                b0 = fdot2f(w2p0[32 + kk + 1], v2, b0);  b1 = fdot2f(w2p1[32 + kk + 1], v2, b1);
            }
            a0 += b0; a1 += b1;

            // prefetch x_{t+1} into XA (read next step in L0; barrier below orders it)
            if (t + 1 < TT && tid < GS * IN_DIM) {
                const int ss = tid / IN_DIM, ii = tid % IN_DIM;
                ((h16*)&XA[ss][0])[ii] =
                    (h16)x[(size_t)(b4 + ss) * (IN_DIM * TT) + ii * TT + (t + 1)];
            }

            const float pa0 = __shfl_xor(a0, 1);
            const float pa1 = __shfl_xor(a1, 1);
            if (half == 0) {
                const float ig = sigf(a0), fg = sigf(a1), gg = tanhf_(pa0), og = sigf(pa1);
                c2 = fg * c2 + ig * gg;
                const float hv = og * tanhf_(c2);
                hnewh[128 + j] = (h16)hv;
                h2last = hv;
            }
        }
        __syncthreads();
    }

    // final h2 (fp32, from registers) -> FC
    if (half == 0) HF[s][j] = h2last;
    __syncthreads();

    if (tid < GS * 4) {
        const int ss = tid >> 2, o = tid & 3;
        float acc = bfc[o];
        #pragma unroll
        for (int jj = 0; jj < HDIM; ++jj) acc += HF[ss][jj] * wfc[o * HDIM + jj];
        out[(b4 + ss) * 4 + o] = acc;
    }
}

extern "C" void kernel_launch(void* const* d_in, const int* in_sizes, int n_in,
                              void* d_out, int out_size, void* d_ws, size_t ws_size,
                              hipStream_t stream) {
    const float* x    = (const float*)d_in[0];
    const float* wih0 = (const float*)d_in[1];
    const float* whh0 = (const float*)d_in[2];
    const float* bih0 = (const float*)d_in[3];
    const float* bhh0 = (const float*)d_in[4];
    const float* wih1 = (const float*)d_in[5];
    const float* whh1 = (const float*)d_in[6];
    const float* bih1 = (const float*)d_in[7];
    const float* bhh1 = (const float*)d_in[8];
    const float* wih2 = (const float*)d_in[9];
    const float* whh2 = (const float*)d_in[10];
    const float* bih2 = (const float*)d_in[11];
    const float* bhh2 = (const float*)d_in[12];
    const float* wfc  = (const float*)d_in[13];
    const float* bfc  = (const float*)d_in[14];
    float* out = (float*)d_out;

    lstm_fused<<<dim3(BSZ / GS), dim3(NTH), 0, stream>>>(
        x, wih0, whh0, bih0, bhh0, wih1, whh1, bih1, bhh1,
        wih2, whh2, bih2, bhh2, wfc, bfc, out);
}